// Round 2
// baseline (371.751 us; speedup 1.0000x reference)
//
#include <hip/hip_runtime.h>

#define NPTS 4096
#define NB   8
#define BN_EPS 1e-5f
#define MC 16   // column chunks for row-sum pass
#define NC 16   // row chunks for column pass

// ---------------- Kernel 1: fused pointwise MLP -> q, k, v ----------------
// grid 256 x 128 threads ; one thread per point (b,n)
__global__ __launch_bounds__(128) void k1_mlp(
    const float* __restrict__ x,
    const float* __restrict__ w1, const float* __restrict__ g1, const float* __restrict__ b1,
    const float* __restrict__ m1, const float* __restrict__ v1,
    const float* __restrict__ w2,
    const float* __restrict__ wq, const float* __restrict__ gq, const float* __restrict__ bq,
    const float* __restrict__ mq, const float* __restrict__ vq,
    const float* __restrict__ wk, const float* __restrict__ gk, const float* __restrict__ bk,
    const float* __restrict__ mk, const float* __restrict__ vk,
    const float* __restrict__ wv, const float* __restrict__ gv, const float* __restrict__ bv,
    const float* __restrict__ mv, const float* __restrict__ vv,
    const float* __restrict__ offset,
    float* __restrict__ qbuf, float* __restrict__ kbuf, float* __restrict__ aux)
{
    __shared__ __align__(16) float s_w1[64*3];
    __shared__ float s_s1[64], s_t1[64];
    __shared__ __align__(16) float s_w2[128*64];
    __shared__ __align__(16) float s_wqT[128*16];
    __shared__ __align__(16) float s_wkT[128*16];
    __shared__ __align__(16) float s_wvT[128*4];
    __shared__ float s_sq[16], s_tq[16], s_sk[16], s_tk[16], s_sv[4], s_tv[4];

    const int tid = threadIdx.x;
    for (int i = tid; i < 64*3;   i += 128) s_w1[i] = w1[i];
    for (int i = tid; i < 128*64; i += 128) s_w2[i] = w2[i];
    for (int i = tid; i < 16*128; i += 128) {
        int o = i & 127, j = i >> 7;
        s_wqT[o*16 + j] = wq[i];
        s_wkT[o*16 + j] = wk[i];
    }
    for (int i = tid; i < 3*128; i += 128) {
        int o = i & 127, j = i >> 7;
        s_wvT[o*4 + j] = wv[i];
    }
    if (tid < 64) {
        float s = g1[tid] * rsqrtf(v1[tid] + BN_EPS);
        s_s1[tid] = s; s_t1[tid] = b1[tid] - s*m1[tid];
    } else if (tid < 80) {
        int j = tid - 64; float s = gq[j] * rsqrtf(vq[j] + BN_EPS);
        s_sq[j] = s; s_tq[j] = bq[j] - s*mq[j];
    } else if (tid < 96) {
        int j = tid - 80; float s = gk[j] * rsqrtf(vk[j] + BN_EPS);
        s_sk[j] = s; s_tk[j] = bk[j] - s*mk[j];
    } else if (tid < 99) {
        int j = tid - 96; float s = gv[j] * rsqrtf(vv[j] + BN_EPS);
        s_sv[j] = s; s_tv[j] = bv[j] - s*mv[j];
    }
    __syncthreads();

    const int p = blockIdx.x * 128 + tid;   // 0..32767 == b*4096+n
    const int b = p >> 12;
    const int n = p & 4095;
    const float off = offset[0];
    const float* xb = x + (size_t)b*3*NPTS + n;
    const float x0 = xb[0] + off, x1 = xb[NPTS] + off, x2 = xb[2*NPTS] + off;

    float h[64];
#pragma unroll
    for (int c = 0; c < 64; ++c) {
        float d = s_w1[c*3]*x0 + s_w1[c*3+1]*x1 + s_w1[c*3+2]*x2;
        d = s_s1[c]*d + s_t1[c];
        h[c] = fmaxf(d, 0.f);
    }

    float qa[16], ka[16];
#pragma unroll
    for (int j = 0; j < 16; ++j) { qa[j] = 0.f; ka[j] = 0.f; }
    float va0 = 0.f, va1 = 0.f, va2 = 0.f;

    const float4* w2v = (const float4*)s_w2;
    const float4* wqv = (const float4*)s_wqT;
    const float4* wkv = (const float4*)s_wkT;
    const float4* wvv = (const float4*)s_wvT;

    for (int o = 0; o < 128; ++o) {
        float fp0 = 0.f, fp1 = 0.f, fp2 = 0.f, fp3 = 0.f;
#pragma unroll
        for (int c4 = 0; c4 < 16; c4 += 4) {
            float4 wA = w2v[o*16 + c4 + 0];
            float4 wB = w2v[o*16 + c4 + 1];
            float4 wC = w2v[o*16 + c4 + 2];
            float4 wD = w2v[o*16 + c4 + 3];
            fp0 += (wA.x*h[c4*4+0]  + wA.y*h[c4*4+1])  + (wA.z*h[c4*4+2]  + wA.w*h[c4*4+3]);
            fp1 += (wB.x*h[c4*4+4]  + wB.y*h[c4*4+5])  + (wB.z*h[c4*4+6]  + wB.w*h[c4*4+7]);
            fp2 += (wC.x*h[c4*4+8]  + wC.y*h[c4*4+9])  + (wC.z*h[c4*4+10] + wC.w*h[c4*4+11]);
            fp3 += (wD.x*h[c4*4+12] + wD.y*h[c4*4+13]) + (wD.z*h[c4*4+14] + wD.w*h[c4*4+15]);
        }
        const float f = (fp0 + fp1) + (fp2 + fp3);
#pragma unroll
        for (int j4 = 0; j4 < 4; ++j4) {
            float4 a = wqv[o*4 + j4];
            qa[j4*4+0] += a.x*f; qa[j4*4+1] += a.y*f;
            qa[j4*4+2] += a.z*f; qa[j4*4+3] += a.w*f;
            float4 c = wkv[o*4 + j4];
            ka[j4*4+0] += c.x*f; ka[j4*4+1] += c.y*f;
            ka[j4*4+2] += c.z*f; ka[j4*4+3] += c.w*f;
        }
        float4 wv4 = wvv[o];
        va0 += wv4.x*f; va1 += wv4.y*f; va2 += wv4.z*f;
    }

    float* qrow = qbuf + (size_t)p*16;
    float* krow = kbuf + (size_t)p*16;
#pragma unroll
    for (int j = 0; j < 16; ++j) {
        qrow[j] = fmaxf(s_sq[j]*qa[j] + s_tq[j], 0.f);
        krow[j] = fmaxf(s_sk[j]*ka[j] + s_tk[j], 0.f);
    }
    float* ar = aux + (size_t)p*4;
    ar[0] = fmaxf(s_sv[0]*va0 + s_tv[0], 0.f);
    ar[1] = fmaxf(s_sv[1]*va1 + s_tv[1], 0.f);
    ar[2] = fmaxf(s_sv[2]*va2 + s_tv[2], 0.f);
    // ar[3] (= 1/rowsum) filled by k3
}

// ---------------- Kernel 2: partial row sums of exp(e) ----------------
// grid (MC, 4, NB) x 256 threads; thread handles 4 rows x 256 cols
__global__ __launch_bounds__(256) void k2_rowsum(
    const float* __restrict__ qbuf, const float* __restrict__ kbuf,
    float* __restrict__ psum)
{
    __shared__ __align__(16) float s_k[64*16];
    const int tid = threadIdx.x;
    const int b  = blockIdx.z;
    const int rb = blockIdx.y * 1024;
    const int mb = blockIdx.x * (NPTS / MC);

    float q[4][16];
    int rows[4];
#pragma unroll
    for (int r = 0; r < 4; ++r) {
        const int row = rb + tid + r*256;
        rows[r] = row;
        const float4* qp = (const float4*)(qbuf + ((size_t)b*NPTS + row)*16);
#pragma unroll
        for (int i = 0; i < 4; ++i) {
            float4 t = qp[i];
            q[r][i*4+0] = t.x; q[r][i*4+1] = t.y; q[r][i*4+2] = t.z; q[r][i*4+3] = t.w;
        }
    }

    float sum[4] = {0.f, 0.f, 0.f, 0.f};
    for (int mt = 0; mt < NPTS/MC; mt += 64) {
        __syncthreads();
        ((float4*)s_k)[tid] =
            ((const float4*)(kbuf + ((size_t)b*NPTS + mb + mt)*16))[tid];
        __syncthreads();
        const float4* kv4 = (const float4*)s_k;
        for (int mm = 0; mm < 64; ++mm) {
            float kc[16];
            *(float4*)(kc+0)  = kv4[mm*4+0];
            *(float4*)(kc+4)  = kv4[mm*4+1];
            *(float4*)(kc+8)  = kv4[mm*4+2];
            *(float4*)(kc+12) = kv4[mm*4+3];
            float e[4] = {0.f, 0.f, 0.f, 0.f};
#pragma unroll
            for (int i = 0; i < 16; ++i) {
#pragma unroll
                for (int r = 0; r < 4; ++r) e[r] += q[r][i]*kc[i];
            }
#pragma unroll
            for (int r = 0; r < 4; ++r) sum[r] += __expf(e[r]);
        }
    }

    float* ps = psum + ((size_t)b*MC + blockIdx.x)*NPTS;
#pragma unroll
    for (int r = 0; r < 4; ++r) ps[rows[r]] = sum[r];
}

// ---------------- Kernel 3: reduce row sums, pack 1/rowsum into aux ----------------
__global__ __launch_bounds__(256) void k3_rowred(
    const float* __restrict__ psum, float* __restrict__ aux)
{
    const int p = blockIdx.x*256 + threadIdx.x;   // b*4096+n
    const int b = p >> 12;
    const int n = p & 4095;
    float s = 0.f;
#pragma unroll
    for (int c = 0; c < MC; ++c) s += psum[((size_t)b*MC + c)*NPTS + n];
    aux[(size_t)p*4 + 3] = 1.0f / s;
}

// ---------------- Kernel 4: column pass partials ----------------
// grid (NC, 4, NB) x 256 threads; thread handles 4 cols x 256 rows
__global__ __launch_bounds__(256) void k4_colacc(
    const float* __restrict__ qbuf, const float* __restrict__ kbuf,
    const float* __restrict__ aux, float* __restrict__ pcol)
{
    __shared__ __align__(16) float s_q[64*16];
    __shared__ __align__(16) float s_aux[64*4];
    const int tid = threadIdx.x;
    const int b  = blockIdx.z;
    const int cb = blockIdx.y * 1024;
    const int nb = blockIdx.x * (NPTS / NC);

    float kk[4][16];
    int cols[4];
#pragma unroll
    for (int r = 0; r < 4; ++r) {
        const int col = cb + tid + r*256;
        cols[r] = col;
        const float4* kp = (const float4*)(kbuf + ((size_t)b*NPTS + col)*16);
#pragma unroll
        for (int i = 0; i < 4; ++i) {
            float4 t = kp[i];
            kk[r][i*4+0] = t.x; kk[r][i*4+1] = t.y; kk[r][i*4+2] = t.z; kk[r][i*4+3] = t.w;
        }
    }

    float sacc[4] = {0.f,0.f,0.f,0.f};
    float a0[4]   = {0.f,0.f,0.f,0.f};
    float a1[4]   = {0.f,0.f,0.f,0.f};
    float a2[4]   = {0.f,0.f,0.f,0.f};

    for (int nt0 = 0; nt0 < NPTS/NC; nt0 += 64) {
        __syncthreads();
        ((float4*)s_q)[tid] =
            ((const float4*)(qbuf + ((size_t)b*NPTS + nb + nt0)*16))[tid];
        if (tid < 64)
            ((float4*)s_aux)[tid] =
                ((const float4*)(aux + ((size_t)b*NPTS + nb + nt0)*4))[tid];
        __syncthreads();
        const float4* qv4 = (const float4*)s_q;
        const float4* av4 = (const float4*)s_aux;
        for (int nn = 0; nn < 64; ++nn) {
            float qc[16];
            *(float4*)(qc+0)  = qv4[nn*4+0];
            *(float4*)(qc+4)  = qv4[nn*4+1];
            *(float4*)(qc+8)  = qv4[nn*4+2];
            *(float4*)(qc+12) = qv4[nn*4+3];
            const float4 av = av4[nn];   // {v0, v1, v2, 1/rowsum}
            float e[4] = {0.f,0.f,0.f,0.f};
#pragma unroll
            for (int i = 0; i < 16; ++i) {
#pragma unroll
                for (int r = 0; r < 4; ++r) e[r] += kk[r][i]*qc[i];
            }
#pragma unroll
            for (int r = 0; r < 4; ++r) {
                const float w = __expf(e[r]) * av.w;
                sacc[r] += w;
                a0[r] += av.x*w; a1[r] += av.y*w; a2[r] += av.z*w;
            }
        }
    }

    float* pc = pcol + ((size_t)b*NC + blockIdx.x)*4*NPTS;
#pragma unroll
    for (int r = 0; r < 4; ++r) {
        pc[0*NPTS + cols[r]] = sacc[r];
        pc[1*NPTS + cols[r]] = a0[r];
        pc[2*NPTS + cols[r]] = a1[r];
        pc[3*NPTS + cols[r]] = a2[r];
    }
}

// ---------------- Kernel 5: reduce column partials + epilogue ----------------
__global__ __launch_bounds__(256) void k5_final(
    const float* __restrict__ pcol, const float* __restrict__ x,
    const float* __restrict__ alpha, float* __restrict__ out)
{
    const int p = blockIdx.x*256 + threadIdx.x;   // b*4096+m
    const int b = p >> 12;
    const int m = p & 4095;
    float s = 0.f, a0 = 0.f, a1 = 0.f, a2 = 0.f;
#pragma unroll
    for (int c = 0; c < NC; ++c) {
        const float* pc = pcol + ((size_t)b*NC + c)*4*NPTS;
        s  += pc[0*NPTS + m];
        a0 += pc[1*NPTS + m];
        a1 += pc[2*NPTS + m];
        a2 += pc[3*NPTS + m];
    }
    const float sc = alpha[0] / (1e-9f + s);
    const float* xb = x + (size_t)b*3*NPTS + m;
    float* ob = out + (size_t)b*3*NPTS + m;
    ob[0*NPTS] = a0*sc + xb[0*NPTS];
    ob[1*NPTS] = a1*sc + xb[1*NPTS];
    ob[2*NPTS] = a2*sc + xb[2*NPTS];
}

extern "C" void kernel_launch(void* const* d_in, const int* in_sizes, int n_in,
                              void* d_out, int out_size, void* d_ws, size_t ws_size,
                              hipStream_t stream) {
    const float* x      = (const float*)d_in[0];
    const float* w1     = (const float*)d_in[1];
    const float* g1     = (const float*)d_in[2];
    const float* b1     = (const float*)d_in[3];
    const float* m1     = (const float*)d_in[4];
    const float* v1     = (const float*)d_in[5];
    const float* w2     = (const float*)d_in[6];
    const float* wq     = (const float*)d_in[7];
    const float* gq     = (const float*)d_in[8];
    const float* bq     = (const float*)d_in[9];
    const float* mq     = (const float*)d_in[10];
    const float* vq     = (const float*)d_in[11];
    const float* wk     = (const float*)d_in[12];
    const float* gk     = (const float*)d_in[13];
    const float* bk     = (const float*)d_in[14];
    const float* mk     = (const float*)d_in[15];
    const float* vk     = (const float*)d_in[16];
    const float* wv     = (const float*)d_in[17];
    const float* gv     = (const float*)d_in[18];
    const float* bv     = (const float*)d_in[19];
    const float* mv     = (const float*)d_in[20];
    const float* vv     = (const float*)d_in[21];
    const float* alpha  = (const float*)d_in[22];
    const float* offset = (const float*)d_in[23];

    char* ws = (char*)d_ws;
    float* qbuf = (float*)(ws);                               // 8*4096*16*4 = 2 MiB
    float* kbuf = (float*)(ws + (size_t)2*1024*1024);         // 2 MiB
    float* aux  = (float*)(ws + (size_t)4*1024*1024);         // 8*4096*4*4 = 512 KiB
    float* psum = (float*)(ws + (size_t)4*1024*1024 + 512*1024);          // 8*16*4096*4 = 2 MiB
    float* pcol = (float*)(ws + (size_t)6*1024*1024 + 512*1024);          // 8*16*4*4096*4 = 8 MiB

    k1_mlp<<<dim3(256), dim3(128), 0, stream>>>(
        x, w1, g1, b1, m1, v1, w2,
        wq, gq, bq, mq, vq,
        wk, gk, bk, mk, vk,
        wv, gv, bv, mv, vv,
        offset, qbuf, kbuf, aux);

    k2_rowsum<<<dim3(MC, 4, NB), dim3(256), 0, stream>>>(qbuf, kbuf, psum);
    k3_rowred<<<dim3(128), dim3(256), 0, stream>>>(psum, aux);
    k4_colacc<<<dim3(NC, 4, NB), dim3(256), 0, stream>>>(qbuf, kbuf, aux, pcol);
    k5_final<<<dim3(128), dim3(256), 0, stream>>>(pcol, x, alpha, (float*)d_out);
}

// Round 3
// 180.133 us; speedup vs baseline: 2.0638x; 2.0638x over previous
//
#include <hip/hip_runtime.h>

#define NPTS 4096
#define NB   8
#define BN_EPS 1e-5f
#define LOG2E 1.4426950408889634f
#define SLICES 4   // n/m slices per pass for occupancy

typedef float f32x16 __attribute__((ext_vector_type(16)));
typedef short bf16x8 __attribute__((ext_vector_type(8)));
typedef unsigned short ushort_t;

#if __has_builtin(__builtin_amdgcn_exp2f)
#define EXP2(x) __builtin_amdgcn_exp2f(x)
#else
#define EXP2(x) exp2f(x)
#endif

__device__ __forceinline__ ushort_t f2bf(float f) {
    unsigned u = __builtin_bit_cast(unsigned, f);
    unsigned r = (u + 0x7FFFu + ((u >> 16) & 1u)) >> 16;
    return (ushort_t)r;
}

// ---------------- k0: fold BN + combine head weights with w2 ----------------
// grid 36 x 64.  blocks 0..34: Wc[j][c] = post_j * s_j * sum_o Whead[j][o]*w2[o][c]
// block 35: w1s (BN1 scale folded into w1) and t1.
__global__ __launch_bounds__(64) void k0_prep(
    const float* __restrict__ w1, const float* __restrict__ g1, const float* __restrict__ b1,
    const float* __restrict__ m1, const float* __restrict__ v1,
    const float* __restrict__ w2,
    const float* __restrict__ wq, const float* __restrict__ gq, const float* __restrict__ bq,
    const float* __restrict__ mq, const float* __restrict__ vq,
    const float* __restrict__ wk, const float* __restrict__ gk, const float* __restrict__ bk,
    const float* __restrict__ mk, const float* __restrict__ vk,
    const float* __restrict__ wv, const float* __restrict__ gv, const float* __restrict__ bv,
    const float* __restrict__ mv, const float* __restrict__ vv,
    float* __restrict__ Wc, float* __restrict__ tb,
    float* __restrict__ w1s, float* __restrict__ t1)
{
    const int j = blockIdx.x;
    const int c = threadIdx.x;
    if (j == 35) {
        float s = g1[c] * rsqrtf(v1[c] + BN_EPS);
        w1s[c*3+0] = s * w1[c*3+0];
        w1s[c*3+1] = s * w1[c*3+1];
        w1s[c*3+2] = s * w1[c*3+2];
        t1[c] = b1[c] - s * m1[c];
        return;
    }
    const float* wrow;
    float g, bb, mm, vr, post = 1.f;
    if (j < 16)      { wrow = wq + j*128;      g = gq[j];    bb = bq[j];    mm = mq[j];    vr = vq[j];    post = LOG2E; }
    else if (j < 32) { int t = j-16; wrow = wk + t*128; g = gk[t]; bb = bk[t]; mm = mk[t]; vr = vk[t]; }
    else             { int t = j-32; wrow = wv + t*128; g = gv[t]; bb = bv[t]; mm = mv[t]; vr = vv[t]; }
    const float sbn = g * rsqrtf(vr + BN_EPS);
    float acc = 0.f;
    for (int o = 0; o < 128; ++o) acc += wrow[o] * w2[o*64 + c];
    Wc[j*64 + c] = post * sbn * acc;
    if (c == 0) tb[j] = post * (bb - sbn * mm);
}

// ---------------- k1: per-point MLP -> q(bf16, xlog2e), k(bf16), v(aux f32) ----
// grid 128 x 256; one thread per point.
__global__ __launch_bounds__(256) void k1_mlp(
    const float* __restrict__ x, const float* __restrict__ offset,
    const float* __restrict__ Wc, const float* __restrict__ tb,
    const float* __restrict__ w1s, const float* __restrict__ t1,
    ushort_t* __restrict__ qbuf, ushort_t* __restrict__ kbuf, float* __restrict__ aux)
{
    const int p = blockIdx.x*256 + threadIdx.x;
    const int b = p >> 12;
    const int n = p & 4095;
    const float off = offset[0];
    const float* xb = x + (size_t)b*3*NPTS + n;
    const float x0 = xb[0] + off, x1 = xb[NPTS] + off, x2 = xb[2*NPTS] + off;

    float acc[35];
#pragma unroll
    for (int j = 0; j < 35; ++j) acc[j] = tb[j];

    for (int c = 0; c < 64; ++c) {
        const float h = fmaxf(
            fmaf(w1s[c*3+0], x0, fmaf(w1s[c*3+1], x1, fmaf(w1s[c*3+2], x2, t1[c]))), 0.f);
        const float* wc = Wc + c;
#pragma unroll
        for (int j = 0; j < 35; ++j) acc[j] = fmaf(wc[j*64], h, acc[j]);
    }

    unsigned qw[8], kw[8];
#pragma unroll
    for (int i = 0; i < 8; ++i) {
        ushort_t qlo = f2bf(fmaxf(acc[2*i],    0.f));
        ushort_t qhi = f2bf(fmaxf(acc[2*i+1],  0.f));
        qw[i] = (unsigned)qlo | ((unsigned)qhi << 16);
        ushort_t klo = f2bf(fmaxf(acc[16+2*i],   0.f));
        ushort_t khi = f2bf(fmaxf(acc[16+2*i+1], 0.f));
        kw[i] = (unsigned)klo | ((unsigned)khi << 16);
    }
    uint4* qd = (uint4*)(qbuf + (size_t)p*16);
    qd[0] = make_uint4(qw[0], qw[1], qw[2], qw[3]);
    qd[1] = make_uint4(qw[4], qw[5], qw[6], qw[7]);
    uint4* kd = (uint4*)(kbuf + (size_t)p*16);
    kd[0] = make_uint4(kw[0], kw[1], kw[2], kw[3]);
    kd[1] = make_uint4(kw[4], kw[5], kw[6], kw[7]);
    float4* ar = (float4*)(aux + (size_t)p*4);
    *ar = make_float4(fmaxf(acc[32], 0.f), fmaxf(acc[33], 0.f), fmaxf(acc[34], 0.f), 0.f);
}

// ---------------- k2: row sums via MFMA ----------------
// wave w: b = w>>9, nblk = (w&511)>>2, slice = w&3.
// D[row=m, col=n] = sum_i k[i,m]*q[i,n]; lane col n = n0+(lane&31).
__global__ __launch_bounds__(256) void k2_rowsum(
    const ushort_t* __restrict__ qbuf, const ushort_t* __restrict__ kbuf,
    float* __restrict__ psum)
{
    const int lane = threadIdx.x & 63;
    const int w = blockIdx.x*4 + (threadIdx.x >> 6);
    const int b = w >> 9;
    const int r = w & 511;
    const int nblk = r >> 2;
    const int slice = r & 3;
    const int n0 = nblk * 32;
    const int m0 = slice * 1024;

    const bf16x8 qfrag = *(const bf16x8*)(qbuf + ((size_t)b*NPTS + n0 + (lane & 31))*16 + (lane >> 5)*8);
    const ushort_t* kb = kbuf + ((size_t)b*NPTS + m0 + (lane & 31))*16 + (lane >> 5)*8;

    float rsum = 0.f;
    bf16x8 kf = *(const bf16x8*)kb;
    for (int t = 0; t < 32; ++t) {
        const bf16x8 kcur = kf;
        if (t + 1 < 32) kf = *(const bf16x8*)(kb + (size_t)(t+1)*512);
        f32x16 acc;
#pragma unroll
        for (int i = 0; i < 16; ++i) acc[i] = 0.f;
        acc = __builtin_amdgcn_mfma_f32_32x32x16_bf16(kcur, qfrag, acc, 0, 0, 0);
#pragma unroll
        for (int i = 0; i < 16; ++i) rsum += EXP2(acc[i]);
    }
    rsum += __shfl_xor(rsum, 32);
    if (lane < 32) psum[((size_t)slice*NB + b)*NPTS + n0 + lane] = rsum;
}

// ---------------- k3: reduce row sums -> aux.w = 1/rowsum ----------------
__global__ __launch_bounds__(256) void k3_rowred(
    const float* __restrict__ psum, float* __restrict__ aux)
{
    const int p = blockIdx.x*256 + threadIdx.x;
    const int b = p >> 12;
    const int n = p & 4095;
    float s = 0.f;
#pragma unroll
    for (int sl = 0; sl < SLICES; ++sl) s += psum[((size_t)sl*NB + b)*NPTS + n];
    aux[(size_t)p*4 + 3] = 1.0f / s;
}

// ---------------- k4: column pass via MFMA ----------------
// wave w: b = w>>9, mblk = (w&511)>>2, slice = w&3.  A-frag (k at m-block) hoisted.
__global__ __launch_bounds__(256, 4) void k4_colpass(
    const ushort_t* __restrict__ qbuf, const ushort_t* __restrict__ kbuf,
    const float* __restrict__ aux, float* __restrict__ pcol)
{
    const int lane = threadIdx.x & 63;
    const int w = blockIdx.x*4 + (threadIdx.x >> 6);
    const int b = w >> 9;
    const int r = w & 511;
    const int mblk = r >> 2;
    const int slice = r & 3;
    const int m0 = mblk * 32;
    const int n0 = slice * 1024;

    const bf16x8 afrag = *(const bf16x8*)(kbuf + ((size_t)b*NPTS + m0 + (lane & 31))*16 + (lane >> 5)*8);
    const ushort_t* qb = qbuf + ((size_t)b*NPTS + n0 + (lane & 31))*16 + (lane >> 5)*8;
    const float4* auxp = (const float4*)aux + (size_t)b*NPTS + n0 + (lane & 31);

    float S[16], A0[16], A1[16], A2[16];
#pragma unroll
    for (int i = 0; i < 16; ++i) { S[i] = 0.f; A0[i] = 0.f; A1[i] = 0.f; A2[i] = 0.f; }

    bf16x8 qf = *(const bf16x8*)qb;
    float4 ax = auxp[0];
    for (int t = 0; t < 32; ++t) {
        const bf16x8 qcur = qf;
        const float4 axc = ax;
        if (t + 1 < 32) {
            qf = *(const bf16x8*)(qb + (size_t)(t+1)*512);
            ax = auxp[(size_t)(t+1)*32];
        }
        f32x16 acc;
#pragma unroll
        for (int i = 0; i < 16; ++i) acc[i] = 0.f;
        acc = __builtin_amdgcn_mfma_f32_32x32x16_bf16(afrag, qcur, acc, 0, 0, 0);
#pragma unroll
        for (int i = 0; i < 16; ++i) {
            const float wgt = EXP2(acc[i]) * axc.w;
            S[i]  += wgt;
            A0[i] = fmaf(axc.x, wgt, A0[i]);
            A1[i] = fmaf(axc.y, wgt, A1[i]);
            A2[i] = fmaf(axc.z, wgt, A2[i]);
        }
    }

    // allreduce over the 32 columns (low 5 lane bits)
#pragma unroll
    for (int d = 1; d <= 16; d <<= 1) {
#pragma unroll
        for (int i = 0; i < 16; ++i) {
            S[i]  += __shfl_xor(S[i],  d);
            A0[i] += __shfl_xor(A0[i], d);
            A1[i] += __shfl_xor(A1[i], d);
            A2[i] += __shfl_xor(A2[i], d);
        }
    }

    if ((lane & 31) == 0) {
        const int hi = lane >> 5;
        float* base = pcol + (((size_t)b*SLICES + slice)*4)*NPTS;
#pragma unroll
        for (int i = 0; i < 16; ++i) {
            const int m = m0 + (i & 3) + 8*(i >> 2) + 4*hi;
            base[0*NPTS + m] = S[i];
            base[1*NPTS + m] = A0[i];
            base[2*NPTS + m] = A1[i];
            base[3*NPTS + m] = A2[i];
        }
    }
}

// ---------------- k5: reduce slices + epilogue ----------------
__global__ __launch_bounds__(256) void k5_final(
    const float* __restrict__ pcol, const float* __restrict__ x,
    const float* __restrict__ alpha, float* __restrict__ out)
{
    const int p = blockIdx.x*256 + threadIdx.x;
    const int b = p >> 12;
    const int m = p & 4095;
    float s = 0.f, a0 = 0.f, a1 = 0.f, a2 = 0.f;
#pragma unroll
    for (int sl = 0; sl < SLICES; ++sl) {
        const float* base = pcol + (((size_t)b*SLICES + sl)*4)*NPTS;
        s  += base[0*NPTS + m];
        a0 += base[1*NPTS + m];
        a1 += base[2*NPTS + m];
        a2 += base[3*NPTS + m];
    }
    const float sc = alpha[0] / (1e-9f + s);
    const float* xb = x + (size_t)b*3*NPTS + m;
    float* ob = out + (size_t)b*3*NPTS + m;
    ob[0*NPTS] = fmaf(a0, sc, xb[0*NPTS]);
    ob[1*NPTS] = fmaf(a1, sc, xb[1*NPTS]);
    ob[2*NPTS] = fmaf(a2, sc, xb[2*NPTS]);
}

extern "C" void kernel_launch(void* const* d_in, const int* in_sizes, int n_in,
                              void* d_out, int out_size, void* d_ws, size_t ws_size,
                              hipStream_t stream) {
    const float* x      = (const float*)d_in[0];
    const float* w1     = (const float*)d_in[1];
    const float* g1     = (const float*)d_in[2];
    const float* b1     = (const float*)d_in[3];
    const float* m1     = (const float*)d_in[4];
    const float* v1     = (const float*)d_in[5];
    const float* w2     = (const float*)d_in[6];
    const float* wq     = (const float*)d_in[7];
    const float* gq     = (const float*)d_in[8];
    const float* bq     = (const float*)d_in[9];
    const float* mq     = (const float*)d_in[10];
    const float* vq     = (const float*)d_in[11];
    const float* wk     = (const float*)d_in[12];
    const float* gk     = (const float*)d_in[13];
    const float* bk     = (const float*)d_in[14];
    const float* mk     = (const float*)d_in[15];
    const float* vk     = (const float*)d_in[16];
    const float* wv     = (const float*)d_in[17];
    const float* gv     = (const float*)d_in[18];
    const float* bv     = (const float*)d_in[19];
    const float* mv     = (const float*)d_in[20];
    const float* vv     = (const float*)d_in[21];
    const float* alpha  = (const float*)d_in[22];
    const float* offset = (const float*)d_in[23];

    char* ws = (char*)d_ws;
    float*    Wc   = (float*)(ws + 0);                      //  9 KB
    float*    tb   = (float*)(ws + 16*1024);                //  140 B
    float*    w1s  = (float*)(ws + 32*1024);                //  768 B
    float*    t1   = (float*)(ws + 48*1024);                //  256 B
    ushort_t* qbuf = (ushort_t*)(ws + 64*1024);             //  1 MiB
    ushort_t* kbuf = (ushort_t*)(ws + 64*1024 + (size_t)1*1024*1024);   // 1 MiB
    float*    aux  = (float*)(ws + 64*1024 + (size_t)2*1024*1024);      // 512 KiB
    float*    psum = (float*)(ws + 64*1024 + (size_t)2*1024*1024 + 512*1024); // 512 KiB
    float*    pcol = (float*)(ws + 64*1024 + (size_t)3*1024*1024);      // 2 MiB

    k0_prep<<<dim3(36), dim3(64), 0, stream>>>(
        w1, g1, b1, m1, v1, w2,
        wq, gq, bq, mq, vq,
        wk, gk, bk, mk, vk,
        wv, gv, bv, mv, vv,
        Wc, tb, w1s, t1);

    k1_mlp<<<dim3(128), dim3(256), 0, stream>>>(
        x, offset, Wc, tb, w1s, t1, qbuf, kbuf, aux);

    k2_rowsum<<<dim3(1024), dim3(256), 0, stream>>>(qbuf, kbuf, psum);
    k3_rowred<<<dim3(128), dim3(256), 0, stream>>>(psum, aux);
    k4_colpass<<<dim3(1024), dim3(256), 0, stream>>>(qbuf, kbuf, aux, pcol);
    k5_final<<<dim3(128), dim3(256), 0, stream>>>(pcol, x, alpha, (float*)d_out);
}

// Round 5
// 174.606 us; speedup vs baseline: 2.1291x; 1.0317x over previous
//
#include <hip/hip_runtime.h>

#define NPTS 4096
#define NB   8
#define BN_EPS 1e-5f
#define LOG2E 1.4426950408889634f
#define RS_SLICES 8   // m-slices in row-sum pass (k2)
#define CS_SLICES 4   // n-slices in column pass (k4)

typedef float f32x16 __attribute__((ext_vector_type(16)));
typedef float f32x4  __attribute__((ext_vector_type(4)));
typedef short bf16x8 __attribute__((ext_vector_type(8)));
typedef unsigned short ushort_t;

#if __has_builtin(__builtin_amdgcn_exp2f)
#define EXP2(x) __builtin_amdgcn_exp2f(x)
#else
#define EXP2(x) exp2f(x)
#endif

__device__ __forceinline__ ushort_t f2bf(float f) {
    unsigned u = __builtin_bit_cast(unsigned, f);
    unsigned r = (u + 0x7FFFu + ((u >> 16) & 1u)) >> 16;
    return (ushort_t)r;
}

// ---------------- k0: fold BN + combine head weights with w2 ----------------
// grid 36 x 256. blocks 0..34: Wc[j][c]; block 35: w1s, t1.
__global__ __launch_bounds__(256) void k0_prep(
    const float* __restrict__ w1, const float* __restrict__ g1, const float* __restrict__ b1,
    const float* __restrict__ m1, const float* __restrict__ v1,
    const float* __restrict__ w2,
    const float* __restrict__ wq, const float* __restrict__ gq, const float* __restrict__ bq,
    const float* __restrict__ mq, const float* __restrict__ vq,
    const float* __restrict__ wk, const float* __restrict__ gk, const float* __restrict__ bk,
    const float* __restrict__ mk, const float* __restrict__ vk,
    const float* __restrict__ wv, const float* __restrict__ gv, const float* __restrict__ bv,
    const float* __restrict__ mv, const float* __restrict__ vv,
    float* __restrict__ Wc, float* __restrict__ tb,
    float* __restrict__ w1s, float* __restrict__ t1)
{
    const int j = blockIdx.x;
    const int t = threadIdx.x;
    if (j == 35) {
        if (t < 64) {
            float s = g1[t] * rsqrtf(v1[t] + BN_EPS);
            w1s[t*3+0] = s * w1[t*3+0];
            w1s[t*3+1] = s * w1[t*3+1];
            w1s[t*3+2] = s * w1[t*3+2];
            t1[t] = b1[t] - s * m1[t];
        }
        return;
    }
    __shared__ float red[256];
    const int c = t & 63;
    const int chunk = t >> 6;
    const float* wrow;
    float g, bb, mm, vr, post = 1.f;
    if (j < 16)      { wrow = wq + j*128;      g = gq[j];    bb = bq[j];    mm = mq[j];    vr = vq[j];    post = LOG2E; }
    else if (j < 32) { int u = j-16; wrow = wk + u*128; g = gk[u]; bb = bk[u]; mm = mk[u]; vr = vk[u]; }
    else             { int u = j-32; wrow = wv + u*128; g = gv[u]; bb = bv[u]; mm = mv[u]; vr = vv[u]; }
    float acc = 0.f;
    for (int o = chunk*32; o < chunk*32 + 32; ++o) acc = fmaf(wrow[o], w2[o*64 + c], acc);
    red[t] = acc;
    __syncthreads();
    if (t < 64) {
        const float s4 = red[t] + red[64+t] + red[128+t] + red[192+t];
        const float sbn = g * rsqrtf(vr + BN_EPS);
        Wc[j*64 + t] = post * sbn * s4;
        if (t == 0) tb[j] = post * (bb - sbn * mm);
    }
}

// ---------------- k1: per-point MLP -> q(bf16, xlog2e), k(bf16), v(aux f32) ----
__global__ __launch_bounds__(128) void k1_mlp(
    const float* __restrict__ x, const float* __restrict__ offset,
    const float* __restrict__ Wc, const float* __restrict__ tb,
    const float* __restrict__ w1s, const float* __restrict__ t1,
    ushort_t* __restrict__ qbuf, ushort_t* __restrict__ kbuf, float* __restrict__ aux)
{
    const int p = blockIdx.x*128 + threadIdx.x;
    const int b = p >> 12;
    const int n = p & 4095;
    const float off = offset[0];
    const float* xb = x + (size_t)b*3*NPTS + n;
    const float x0 = xb[0] + off, x1 = xb[NPTS] + off, x2 = xb[2*NPTS] + off;

    float acc[35];
#pragma unroll
    for (int j = 0; j < 35; ++j) acc[j] = tb[j];

    for (int c = 0; c < 64; ++c) {
        const float h = fmaxf(
            fmaf(w1s[c*3+0], x0, fmaf(w1s[c*3+1], x1, fmaf(w1s[c*3+2], x2, t1[c]))), 0.f);
        const float* wc = Wc + c;
#pragma unroll
        for (int j = 0; j < 35; ++j) acc[j] = fmaf(wc[j*64], h, acc[j]);
    }

    unsigned qw[8], kw[8];
#pragma unroll
    for (int i = 0; i < 8; ++i) {
        ushort_t qlo = f2bf(fmaxf(acc[2*i],    0.f));
        ushort_t qhi = f2bf(fmaxf(acc[2*i+1],  0.f));
        qw[i] = (unsigned)qlo | ((unsigned)qhi << 16);
        ushort_t klo = f2bf(fmaxf(acc[16+2*i],   0.f));
        ushort_t khi = f2bf(fmaxf(acc[16+2*i+1], 0.f));
        kw[i] = (unsigned)klo | ((unsigned)khi << 16);
    }
    uint4* qd = (uint4*)(qbuf + (size_t)p*16);
    qd[0] = make_uint4(qw[0], qw[1], qw[2], qw[3]);
    qd[1] = make_uint4(qw[4], qw[5], qw[6], qw[7]);
    uint4* kd = (uint4*)(kbuf + (size_t)p*16);
    kd[0] = make_uint4(kw[0], kw[1], kw[2], kw[3]);
    kd[1] = make_uint4(kw[4], kw[5], kw[6], kw[7]);
    float4* ar = (float4*)(aux + (size_t)p*4);
    *ar = make_float4(fmaxf(acc[32], 0.f), fmaxf(acc[33], 0.f), fmaxf(acc[34], 0.f), 0.f);
}

// ---------------- k2: row sums via 32x32x16 MFMA, 8 m-slices ----------------
// wave w: b = w>>10, nblk = (w&1023)>>3, slice = w&7.
__global__ __launch_bounds__(256, 8) void k2_rowsum(
    const ushort_t* __restrict__ qbuf, const ushort_t* __restrict__ kbuf,
    float* __restrict__ psum)
{
    const int lane = threadIdx.x & 63;
    const int w = blockIdx.x*4 + (threadIdx.x >> 6);
    const int b = w >> 10;
    const int r = w & 1023;
    const int nblk = r >> 3;
    const int slice = r & 7;
    const int n0 = nblk * 32;
    const int m0 = slice * 512;

    const bf16x8 qfrag = *(const bf16x8*)(qbuf + ((size_t)b*NPTS + n0 + (lane & 31))*16 + (lane >> 5)*8);
    const ushort_t* kb = kbuf + ((size_t)b*NPTS + m0 + (lane & 31))*16 + (lane >> 5)*8;

    float rsum = 0.f;
    bf16x8 kf = *(const bf16x8*)kb;
    for (int t = 0; t < 16; ++t) {
        const bf16x8 kcur = kf;
        if (t + 1 < 16) kf = *(const bf16x8*)(kb + (size_t)(t+1)*512);
        f32x16 acc;
#pragma unroll
        for (int i = 0; i < 16; ++i) acc[i] = 0.f;
        acc = __builtin_amdgcn_mfma_f32_32x32x16_bf16(kcur, qfrag, acc, 0, 0, 0);
#pragma unroll
        for (int i = 0; i < 16; ++i) rsum += EXP2(acc[i]);
    }
    rsum += __shfl_xor(rsum, 32);
    if (lane < 32) psum[((size_t)slice*NB + b)*NPTS + n0 + lane] = rsum;
}

// ---------------- k3: reduce row sums -> aux.w = 1/rowsum ----------------
__global__ __launch_bounds__(256) void k3_rowred(
    const float* __restrict__ psum, float* __restrict__ aux)
{
    const int p = blockIdx.x*256 + threadIdx.x;
    const int b = p >> 12;
    const int n = p & 4095;
    float s = 0.f;
#pragma unroll
    for (int sl = 0; sl < RS_SLICES; ++sl) s += psum[((size_t)sl*NB + b)*NPTS + n];
    aux[(size_t)p*4 + 3] = 1.0f / s;
}

// ---------------- k4: column pass via 16x16x32 MFMA (K zero-padded) ----------
// wave w: b = w>>10, mtile = (w&1023)>>2, slice = w&3.
// A = k[m-tile rows], B = q[n cols]; D[row=m: (lane>>4)*4+reg, col=n: lane&15].
__global__ __launch_bounds__(256, 8) void k4_colpass(
    const ushort_t* __restrict__ qbuf, const ushort_t* __restrict__ kbuf,
    const float* __restrict__ aux, float* __restrict__ pcol)
{
    const int lane = threadIdx.x & 63;
    const int w = blockIdx.x*4 + (threadIdx.x >> 6);
    const int b = w >> 10;
    const int r = w & 1023;
    const int mtile = r >> 2;
    const int slice = r & 3;
    const int m0 = mtile * 16;
    const int n0 = slice * 1024;
    const int g = lane >> 4;          // K-group 0..3; groups 2,3 are zero pad
    const int lc = lane & 15;

    const bf16x8 zero8 = {0,0,0,0,0,0,0,0};
    bf16x8 afrag = zero8;
    if (g < 2) afrag = *(const bf16x8*)(kbuf + ((size_t)b*NPTS + m0 + lc)*16 + g*8);

    const ushort_t* qb = qbuf + ((size_t)b*NPTS + n0 + lc)*16 + g*8;
    const float4* auxp = (const float4*)aux + (size_t)b*NPTS + n0 + lc;

    float S[4]  = {0.f,0.f,0.f,0.f};
    float A0[4] = {0.f,0.f,0.f,0.f};
    float A1[4] = {0.f,0.f,0.f,0.f};
    float A2[4] = {0.f,0.f,0.f,0.f};

    bf16x8 qf = zero8;
    if (g < 2) qf = *(const bf16x8*)qb;
    float4 ax = auxp[0];
    for (int t = 0; t < 64; ++t) {
        const bf16x8 qcur = qf;
        const float4 axc = ax;
        if (t + 1 < 64) {
            if (g < 2) qf = *(const bf16x8*)(qb + (size_t)(t+1)*256);
            ax = auxp[(size_t)(t+1)*16];
        }
        f32x4 acc;
#pragma unroll
        for (int i = 0; i < 4; ++i) acc[i] = 0.f;
        acc = __builtin_amdgcn_mfma_f32_16x16x32_bf16(afrag, qcur, acc, 0, 0, 0);
#pragma unroll
        for (int i = 0; i < 4; ++i) {
            const float wgt = EXP2(acc[i]) * axc.w;
            S[i]  += wgt;
            A0[i] = fmaf(axc.x, wgt, A0[i]);
            A1[i] = fmaf(axc.y, wgt, A1[i]);
            A2[i] = fmaf(axc.z, wgt, A2[i]);
        }
    }

    // reduce over the 16 n-columns (lane bits 0..3)
#pragma unroll
    for (int d = 1; d <= 8; d <<= 1) {
#pragma unroll
        for (int i = 0; i < 4; ++i) {
            S[i]  += __shfl_xor(S[i],  d);
            A0[i] += __shfl_xor(A0[i], d);
            A1[i] += __shfl_xor(A1[i], d);
            A2[i] += __shfl_xor(A2[i], d);
        }
    }

    if (lc == 0) {
        float* base = pcol + (((size_t)b*CS_SLICES + slice)*4)*NPTS;
#pragma unroll
        for (int i = 0; i < 4; ++i) {
            const int m = m0 + g*4 + i;
            base[0*NPTS + m] = S[i];
            base[1*NPTS + m] = A0[i];
            base[2*NPTS + m] = A1[i];
            base[3*NPTS + m] = A2[i];
        }
    }
}

// ---------------- k5: reduce slices + epilogue ----------------
__global__ __launch_bounds__(256) void k5_final(
    const float* __restrict__ pcol, const float* __restrict__ x,
    const float* __restrict__ alpha, float* __restrict__ out)
{
    const int p = blockIdx.x*256 + threadIdx.x;
    const int b = p >> 12;
    const int m = p & 4095;
    float s = 0.f, a0 = 0.f, a1 = 0.f, a2 = 0.f;
#pragma unroll
    for (int sl = 0; sl < CS_SLICES; ++sl) {
        const float* base = pcol + (((size_t)b*CS_SLICES + sl)*4)*NPTS;
        s  += base[0*NPTS + m];
        a0 += base[1*NPTS + m];
        a1 += base[2*NPTS + m];
        a2 += base[3*NPTS + m];
    }
    const float sc = alpha[0] / (1e-9f + s);
    const float* xb = x + (size_t)b*3*NPTS + m;
    float* ob = out + (size_t)b*3*NPTS + m;
    ob[0*NPTS] = fmaf(a0, sc, xb[0*NPTS]);
    ob[1*NPTS] = fmaf(a1, sc, xb[1*NPTS]);
    ob[2*NPTS] = fmaf(a2, sc, xb[2*NPTS]);
}

extern "C" void kernel_launch(void* const* d_in, const int* in_sizes, int n_in,
                              void* d_out, int out_size, void* d_ws, size_t ws_size,
                              hipStream_t stream) {
    const float* x      = (const float*)d_in[0];
    const float* w1     = (const float*)d_in[1];
    const float* g1     = (const float*)d_in[2];
    const float* b1     = (const float*)d_in[3];
    const float* m1     = (const float*)d_in[4];
    const float* v1     = (const float*)d_in[5];
    const float* w2     = (const float*)d_in[6];
    const float* wq     = (const float*)d_in[7];
    const float* gq     = (const float*)d_in[8];
    const float* bq     = (const float*)d_in[9];
    const float* mq     = (const float*)d_in[10];
    const float* vq     = (const float*)d_in[11];
    const float* wk     = (const float*)d_in[12];
    const float* gk     = (const float*)d_in[13];
    const float* bk     = (const float*)d_in[14];
    const float* mk     = (const float*)d_in[15];
    const float* vk     = (const float*)d_in[16];
    const float* wv     = (const float*)d_in[17];
    const float* gv     = (const float*)d_in[18];
    const float* bv     = (const float*)d_in[19];
    const float* mv     = (const float*)d_in[20];
    const float* vv     = (const float*)d_in[21];
    const float* alpha  = (const float*)d_in[22];
    const float* offset = (const float*)d_in[23];

    char* ws = (char*)d_ws;
    float*    Wc   = (float*)(ws + 0);                      //  9 KB
    float*    tb   = (float*)(ws + 16*1024);
    float*    w1s  = (float*)(ws + 32*1024);
    float*    t1   = (float*)(ws + 48*1024);
    ushort_t* qbuf = (ushort_t*)(ws + 64*1024);             //  1 MiB
    ushort_t* kbuf = (ushort_t*)(ws + 64*1024 + (size_t)1*1024*1024);   // 1 MiB
    float*    aux  = (float*)(ws + 64*1024 + (size_t)2*1024*1024);      // 512 KiB
    float*    psum = (float*)(ws + 64*1024 + (size_t)2*1024*1024 + 512*1024); // 1 MiB
    float*    pcol = (float*)(ws + 64*1024 + (size_t)4*1024*1024);      // 2 MiB

    k0_prep<<<dim3(36), dim3(256), 0, stream>>>(
        w1, g1, b1, m1, v1, w2,
        wq, gq, bq, mq, vq,
        wk, gk, bk, mk, vk,
        wv, gv, bv, mv, vv,
        Wc, tb, w1s, t1);

    k1_mlp<<<dim3(256), dim3(128), 0, stream>>>(
        x, offset, Wc, tb, w1s, t1, qbuf, kbuf, aux);

    k2_rowsum<<<dim3(2048), dim3(256), 0, stream>>>(qbuf, kbuf, psum);
    k3_rowred<<<dim3(128), dim3(256), 0, stream>>>(psum, aux);
    k4_colpass<<<dim3(2048), dim3(256), 0, stream>>>(qbuf, kbuf, aux, pcol);
    k5_final<<<dim3(128), dim3(256), 0, stream>>>(pcol, x, alpha, (float*)d_out);
}

// Round 8
// 165.591 us; speedup vs baseline: 2.2450x; 1.0544x over previous
//
#include <hip/hip_runtime.h>

#define NPTS 4096
#define NB   8
#define BN_EPS 1e-5f
#define LOG2E 1.4426950408889634f
#define RS_SLICES 8   // m-slices in row-sum pass (k2)
#define CS_SLICES 4   // n-slices in column pass (k4)

typedef float f32x16 __attribute__((ext_vector_type(16)));
typedef short bf16x8 __attribute__((ext_vector_type(8)));
typedef unsigned short ushort_t;

#if __has_builtin(__builtin_amdgcn_exp2f)
#define EXP2(x) __builtin_amdgcn_exp2f(x)
#else
#define EXP2(x) exp2f(x)
#endif

__device__ __forceinline__ ushort_t f2bf(float f) {
    unsigned u = __builtin_bit_cast(unsigned, f);
    unsigned r = (u + 0x7FFFu + ((u >> 16) & 1u)) >> 16;
    return (ushort_t)r;
}

// ---------------- k0: fold BN + combine head weights with w2 ----------------
__global__ __launch_bounds__(256) void k0_prep(
    const float* __restrict__ w1, const float* __restrict__ g1, const float* __restrict__ b1,
    const float* __restrict__ m1, const float* __restrict__ v1,
    const float* __restrict__ w2,
    const float* __restrict__ wq, const float* __restrict__ gq, const float* __restrict__ bq,
    const float* __restrict__ mq, const float* __restrict__ vq,
    const float* __restrict__ wk, const float* __restrict__ gk, const float* __restrict__ bk,
    const float* __restrict__ mk, const float* __restrict__ vk,
    const float* __restrict__ wv, const float* __restrict__ gv, const float* __restrict__ bv,
    const float* __restrict__ mv, const float* __restrict__ vv,
    float* __restrict__ Wc, float* __restrict__ tb,
    float* __restrict__ w1s, float* __restrict__ t1)
{
    const int j = blockIdx.x;
    const int t = threadIdx.x;
    if (j == 35) {
        if (t < 64) {
            float s = g1[t] * rsqrtf(v1[t] + BN_EPS);
            w1s[t*3+0] = s * w1[t*3+0];
            w1s[t*3+1] = s * w1[t*3+1];
            w1s[t*3+2] = s * w1[t*3+2];
            t1[t] = b1[t] - s * m1[t];
        }
        return;
    }
    __shared__ float red[256];
    const int c = t & 63;
    const int chunk = t >> 6;
    const float* wrow;
    float g, bb, mm, vr, post = 1.f;
    if (j < 16)      { wrow = wq + j*128;      g = gq[j];    bb = bq[j];    mm = mq[j];    vr = vq[j];    post = LOG2E; }
    else if (j < 32) { int u = j-16; wrow = wk + u*128; g = gk[u]; bb = bk[u]; mm = mk[u]; vr = vk[u]; }
    else             { int u = j-32; wrow = wv + u*128; g = gv[u]; bb = bv[u]; mm = mv[u]; vr = vv[u]; }
    float acc = 0.f;
    for (int o = chunk*32; o < chunk*32 + 32; ++o) acc = fmaf(wrow[o], w2[o*64 + c], acc);
    red[t] = acc;
    __syncthreads();
    if (t < 64) {
        const float s4 = red[t] + red[64+t] + red[128+t] + red[192+t];
        const float sbn = g * rsqrtf(vr + BN_EPS);
        Wc[j*64 + t] = post * sbn * s4;
        if (t == 0) tb[j] = post * (bb - sbn * mm);
    }
}

// ---------------- k1: per-point MLP -> q(bf16, xlog2e), k(bf16), v(aux f32) ----
__global__ __launch_bounds__(128) void k1_mlp(
    const float* __restrict__ x, const float* __restrict__ offset,
    const float* __restrict__ Wc, const float* __restrict__ tb,
    const float* __restrict__ w1s, const float* __restrict__ t1,
    ushort_t* __restrict__ qbuf, ushort_t* __restrict__ kbuf, float* __restrict__ aux)
{
    const int p = blockIdx.x*128 + threadIdx.x;
    const int b = p >> 12;
    const int n = p & 4095;
    const float off = offset[0];
    const float* xb = x + (size_t)b*3*NPTS + n;
    const float x0 = xb[0] + off, x1 = xb[NPTS] + off, x2 = xb[2*NPTS] + off;

    float acc[35];
#pragma unroll
    for (int j = 0; j < 35; ++j) acc[j] = tb[j];

    for (int c = 0; c < 64; ++c) {
        const float h = fmaxf(
            fmaf(w1s[c*3+0], x0, fmaf(w1s[c*3+1], x1, fmaf(w1s[c*3+2], x2, t1[c]))), 0.f);
        const float* wc = Wc + c;
#pragma unroll
        for (int j = 0; j < 35; ++j) acc[j] = fmaf(wc[j*64], h, acc[j]);
    }

    unsigned qw[8], kw[8];
#pragma unroll
    for (int i = 0; i < 8; ++i) {
        ushort_t qlo = f2bf(fmaxf(acc[2*i],    0.f));
        ushort_t qhi = f2bf(fmaxf(acc[2*i+1],  0.f));
        qw[i] = (unsigned)qlo | ((unsigned)qhi << 16);
        ushort_t klo = f2bf(fmaxf(acc[16+2*i],   0.f));
        ushort_t khi = f2bf(fmaxf(acc[16+2*i+1], 0.f));
        kw[i] = (unsigned)klo | ((unsigned)khi << 16);
    }
    uint4* qd = (uint4*)(qbuf + (size_t)p*16);
    qd[0] = make_uint4(qw[0], qw[1], qw[2], qw[3]);
    qd[1] = make_uint4(qw[4], qw[5], qw[6], qw[7]);
    uint4* kd = (uint4*)(kbuf + (size_t)p*16);
    kd[0] = make_uint4(kw[0], kw[1], kw[2], kw[3]);
    kd[1] = make_uint4(kw[4], kw[5], kw[6], kw[7]);
    float4* ar = (float4*)(aux + (size_t)p*4);
    *ar = make_float4(fmaxf(acc[32], 0.f), fmaxf(acc[33], 0.f), fmaxf(acc[34], 0.f), 0.f);
}

// ---------------- k2: row sums via 32x32x16 MFMA, 8 m-slices, prefetch-2 ----
__global__ __launch_bounds__(256, 8) void k2_rowsum(
    const ushort_t* __restrict__ qbuf, const ushort_t* __restrict__ kbuf,
    float* __restrict__ psum)
{
    const int lane = threadIdx.x & 63;
    const int w = blockIdx.x*4 + (threadIdx.x >> 6);
    const int b = w >> 10;
    const int r = w & 1023;
    const int nblk = r >> 3;
    const int slice = r & 7;
    const int n0 = nblk * 32;
    const int m0 = slice * 512;

    const bf16x8 qfrag = *(const bf16x8*)(qbuf + ((size_t)b*NPTS + n0 + (lane & 31))*16 + (lane >> 5)*8);
    const ushort_t* kb = kbuf + ((size_t)b*NPTS + m0 + (lane & 31))*16 + (lane >> 5)*8;

    float rs0 = 0.f, rs1 = 0.f, rs2 = 0.f, rs3 = 0.f;
    bf16x8 kf0 = *(const bf16x8*)kb;
    bf16x8 kf1 = *(const bf16x8*)(kb + 512);
    for (int t = 0; t < 16; ++t) {
        const bf16x8 kcur = kf0;
        kf0 = kf1;
        const int tn = (t + 2 < 16) ? t + 2 : 15;
        kf1 = *(const bf16x8*)(kb + (size_t)tn*512);
        f32x16 acc;
#pragma unroll
        for (int i = 0; i < 16; ++i) acc[i] = 0.f;
        acc = __builtin_amdgcn_mfma_f32_32x32x16_bf16(kcur, qfrag, acc, 0, 0, 0);
#pragma unroll
        for (int i = 0; i < 16; i += 4) {
            rs0 += EXP2(acc[i+0]);
            rs1 += EXP2(acc[i+1]);
            rs2 += EXP2(acc[i+2]);
            rs3 += EXP2(acc[i+3]);
        }
    }
    float rsum = (rs0 + rs1) + (rs2 + rs3);
    rsum += __shfl_xor(rsum, 32);
    if (lane < 32) psum[((size_t)slice*NB + b)*NPTS + n0 + lane] = rsum;
}

// ---------------- k3: reduce row sums -> aux = {v*inv, inv} ----------------
__global__ __launch_bounds__(256) void k3_rowred(
    const float* __restrict__ psum, float* __restrict__ aux)
{
    const int p = blockIdx.x*256 + threadIdx.x;
    const int b = p >> 12;
    const int n = p & 4095;
    float s = 0.f;
#pragma unroll
    for (int sl = 0; sl < RS_SLICES; ++sl) s += psum[((size_t)sl*NB + b)*NPTS + n];
    const float inv = 1.0f / s;
    float4* ar = (float4*)(aux + (size_t)p*4);
    float4 v = *ar;
    *ar = make_float4(v.x*inv, v.y*inv, v.z*inv, inv);
}

// ---------------- k4: column pass via 32x32x16 MFMA, prefetch-2 ------------
// wave w: b = w>>9, mtile = (w&511)>>2, slice = w&3.
// A = k[32 m rows], B = q[32 n cols]; D row=m:(i&3)+8*(i>>2)+4*(lane>>5), col=n:lane&31.
__global__ __launch_bounds__(256, 4) void k4_colpass(
    const ushort_t* __restrict__ qbuf, const ushort_t* __restrict__ kbuf,
    const float* __restrict__ aux, float* __restrict__ pcol)
{
    const int lane = threadIdx.x & 63;
    const int w = blockIdx.x*4 + (threadIdx.x >> 6);
    const int b = w >> 9;
    const int r = w & 511;
    const int mtile = r >> 2;
    const int slice = r & 3;
    const int m0 = mtile * 32;
    const int n0 = slice * 1024;

    const bf16x8 afrag = *(const bf16x8*)(kbuf + ((size_t)b*NPTS + m0 + (lane & 31))*16 + (lane >> 5)*8);
    const ushort_t* qb = qbuf + ((size_t)b*NPTS + n0 + (lane & 31))*16 + (lane >> 5)*8;
    const float4* auxp = (const float4*)aux + (size_t)b*NPTS + n0 + (lane & 31);

    float S[16], A0[16], A1[16], A2[16];
#pragma unroll
    for (int i = 0; i < 16; ++i) { S[i] = 0.f; A0[i] = 0.f; A1[i] = 0.f; A2[i] = 0.f; }

    bf16x8 qf0 = *(const bf16x8*)qb;
    bf16x8 qf1 = *(const bf16x8*)(qb + 512);
    float4 ax0 = auxp[0];
    float4 ax1 = auxp[32];
    for (int t = 0; t < 32; ++t) {
        const bf16x8 qcur = qf0;
        const float4 axc = ax0;
        qf0 = qf1; ax0 = ax1;
        const int tn = (t + 2 < 32) ? t + 2 : 31;
        qf1 = *(const bf16x8*)(qb + (size_t)tn*512);
        ax1 = auxp[(size_t)tn*32];
        f32x16 acc;
#pragma unroll
        for (int i = 0; i < 16; ++i) acc[i] = 0.f;
        acc = __builtin_amdgcn_mfma_f32_32x32x16_bf16(afrag, qcur, acc, 0, 0, 0);
#pragma unroll
        for (int i = 0; i < 16; ++i) {
            const float e1 = EXP2(acc[i]);
            S[i]  = fmaf(axc.w, e1, S[i]);
            A0[i] = fmaf(axc.x, e1, A0[i]);
            A1[i] = fmaf(axc.y, e1, A1[i]);
            A2[i] = fmaf(axc.z, e1, A2[i]);
        }
    }

    // allreduce over the 32 columns (low 5 lane bits)
#pragma unroll
    for (int d = 1; d <= 16; d <<= 1) {
#pragma unroll
        for (int i = 0; i < 16; ++i) {
            S[i]  += __shfl_xor(S[i],  d);
            A0[i] += __shfl_xor(A0[i], d);
            A1[i] += __shfl_xor(A1[i], d);
            A2[i] += __shfl_xor(A2[i], d);
        }
    }

    if ((lane & 31) == 0) {
        const int hi = lane >> 5;
        float* base = pcol + (((size_t)b*CS_SLICES + slice)*4)*NPTS;
#pragma unroll
        for (int i = 0; i < 16; ++i) {
            const int m = m0 + (i & 3) + 8*(i >> 2) + 4*hi;
            base[0*NPTS + m] = S[i];
            base[1*NPTS + m] = A0[i];
            base[2*NPTS + m] = A1[i];
            base[3*NPTS + m] = A2[i];
        }
    }
}

// ---------------- k5: reduce slices + epilogue ----------------
__global__ __launch_bounds__(256) void k5_final(
    const float* __restrict__ pcol, const float* __restrict__ x,
    const float* __restrict__ alpha, float* __restrict__ out)
{
    const int p = blockIdx.x*256 + threadIdx.x;
    const int b = p >> 12;
    const int m = p & 4095;
    float s = 0.f, a0 = 0.f, a1 = 0.f, a2 = 0.f;
#pragma unroll
    for (int sl = 0; sl < CS_SLICES; ++sl) {
        const float* base = pcol + (((size_t)b*CS_SLICES + sl)*4)*NPTS;
        s  += base[0*NPTS + m];
        a0 += base[1*NPTS + m];
        a1 += base[2*NPTS + m];
        a2 += base[3*NPTS + m];
    }
    const float sc = alpha[0] / (1e-9f + s);
    const float* xb = x + (size_t)b*3*NPTS + m;
    float* ob = out + (size_t)b*3*NPTS + m;
    ob[0*NPTS] = fmaf(a0, sc, xb[0*NPTS]);
    ob[1*NPTS] = fmaf(a1, sc, xb[1*NPTS]);
    ob[2*NPTS] = fmaf(a2, sc, xb[2*NPTS]);
}

extern "C" void kernel_launch(void* const* d_in, const int* in_sizes, int n_in,
                              void* d_out, int out_size, void* d_ws, size_t ws_size,
                              hipStream_t stream) {
    const float* x      = (const float*)d_in[0];
    const float* w1     = (const float*)d_in[1];
    const float* g1     = (const float*)d_in[2];
    const float* b1     = (const float*)d_in[3];
    const float* m1     = (const float*)d_in[4];
    const float* v1     = (const float*)d_in[5];
    const float* w2     = (const float*)d_in[6];
    const float* wq     = (const float*)d_in[7];
    const float* gq     = (const float*)d_in[8];
    const float* bq     = (const float*)d_in[9];
    const float* mq     = (const float*)d_in[10];
    const float* vq     = (const float*)d_in[11];
    const float* wk     = (const float*)d_in[12];
    const float* gk     = (const float*)d_in[13];
    const float* bk     = (const float*)d_in[14];
    const float* mk     = (const float*)d_in[15];
    const float* vk     = (const float*)d_in[16];
    const float* wv     = (const float*)d_in[17];
    const float* gv     = (const float*)d_in[18];
    const float* bv     = (const float*)d_in[19];
    const float* mv     = (const float*)d_in[20];
    const float* vv     = (const float*)d_in[21];
    const float* alpha  = (const float*)d_in[22];
    const float* offset = (const float*)d_in[23];

    char* ws = (char*)d_ws;
    float*    Wc   = (float*)(ws + 0);
    float*    tb   = (float*)(ws + 16*1024);
    float*    w1s  = (float*)(ws + 32*1024);
    float*    t1   = (float*)(ws + 48*1024);
    ushort_t* qbuf = (ushort_t*)(ws + 64*1024);
    ushort_t* kbuf = (ushort_t*)(ws + 64*1024 + (size_t)1*1024*1024);
    float*    aux  = (float*)(ws + 64*1024 + (size_t)2*1024*1024);
    float*    psum = (float*)(ws + 64*1024 + (size_t)2*1024*1024 + 512*1024);
    float*    pcol = (float*)(ws + 64*1024 + (size_t)4*1024*1024);

    k0_prep<<<dim3(36), dim3(256), 0, stream>>>(
        w1, g1, b1, m1, v1, w2,
        wq, gq, bq, mq, vq,
        wk, gk, bk, mk, vk,
        wv, gv, bv, mv, vv,
        Wc, tb, w1s, t1);

    k1_mlp<<<dim3(256), dim3(128), 0, stream>>>(
        x, offset, Wc, tb, w1s, t1, qbuf, kbuf, aux);

    k2_rowsum<<<dim3(2048), dim3(256), 0, stream>>>(qbuf, kbuf, psum);
    k3_rowred<<<dim3(128), dim3(256), 0, stream>>>(psum, aux);
    k4_colpass<<<dim3(1024), dim3(256), 0, stream>>>(qbuf, kbuf, aux, pcol);
    k5_final<<<dim3(128), dim3(256), 0, stream>>>(pcol, x, alpha, (float*)d_out);
}